// Round 11
// baseline (2157.961 us; speedup 1.0000x reference)
//
#include <hip/hip_runtime.h>
#include <hip/hip_bf16.h>

// Problem constants
#define BB 2
#define SS 1024
#define DD 768
#define HH 12
#define HD 64
#define DFF 3072
#define EPS 1e-5f
#define BS2 (BB * SS)            // 2048
#define BSD ((size_t)BS2 * DD)   // 2048*768
#define GB  768                  // persistent grid: 3 blocks/CU x 256 CUs

typedef unsigned short ushort_t;
typedef unsigned char uchar_t;
using short8 = __attribute__((ext_vector_type(8))) short;
using f32x4  = __attribute__((ext_vector_type(4))) float;

__device__ __forceinline__ ushort_t f2bf_rne(float f) {
    union { float f; unsigned u; } x; x.f = f;
    unsigned r = x.u + 0x7fff + ((x.u >> 16) & 1);
    return (ushort_t)(r >> 16);
}
__device__ __forceinline__ float bf2f(short u) {
    union { unsigned i; float f; } x;
    x.i = ((unsigned)(ushort_t)u) << 16;
    return x.f;
}

// ---------------------------------------------------------------------------
// Shared-memory union across phases (max 48 KB -> 3 blocks/CU)
// ---------------------------------------------------------------------------
union SMem {
    struct {                                  // GEMM phases: 48 KB
        ushort_t As[2][512 * 8];
        ushort_t Bs[2][1024 * 8];
    } g;
    struct {                                  // attention: 44 KB
        ushort_t Ks[2][64 * 64];
        unsigned Vt2[2][64 * 36];
        ushort_t Ps[64 * 72];
        float    r3s[64][4];
    } a;
    struct {                                  // LN / merges
        float reds[4], redss[4], bc[2];
    } r;
};

// ---------------------------------------------------------------------------
// Device-scope grid barrier (all GB blocks co-resident by construction).
// Sense-reversing; counter reset before gen flip so racers can't deadlock.
// ---------------------------------------------------------------------------
__device__ __forceinline__ void grid_barrier(unsigned* cnt, unsigned* gen) {
    __syncthreads();
    __threadfence();                          // release our writes (agent)
    if (threadIdx.x == 0) {
        unsigned g = __hip_atomic_load(gen, __ATOMIC_ACQUIRE, __HIP_MEMORY_SCOPE_AGENT);
        unsigned a = __hip_atomic_fetch_add(cnt, 1u, __ATOMIC_ACQ_REL, __HIP_MEMORY_SCOPE_AGENT);
        if (a + 1 == (unsigned)GB) {
            __hip_atomic_store(cnt, 0u, __ATOMIC_RELAXED, __HIP_MEMORY_SCOPE_AGENT);
            __hip_atomic_fetch_add(gen, 1u, __ATOMIC_RELEASE, __HIP_MEMORY_SCOPE_AGENT);
        } else {
            while (__hip_atomic_load(gen, __ATOMIC_ACQUIRE, __HIP_MEMORY_SCOPE_AGENT) == g)
                __builtin_amdgcn_s_sleep(8);
        }
    }
    __syncthreads();
    __threadfence();                          // acquire others' writes
}

// ---------------------------------------------------------------------------
// prep units: [0, PREP_CVT) weight cvt ; [.., +2048) codes ; [.., +2048) LN1
// ---------------------------------------------------------------------------
#define CVT_N1 (3 * DD * DD / 4)
#define CVT_N2 (CVT_N1 + DD * DD / 4)
#define CVT_N3 (CVT_N2 + DFF * DD / 4)
#define CVT_NT (CVT_N3 + DD * DFF / 4)
#define PREP_CVT   (CVT_NT / 256)
#define PREP_TOT   (PREP_CVT + BB * SS + BS2)

__device__ void prep_unit(SMem& sm, int u,
    const float* qkv_w, const float* o_w, const float* w1, const float* w2,
    ushort_t* wdst, const int* rel, const uchar_t* mask, unsigned* codes,
    const float* x, const float* g, const float* b, ushort_t* y)
{
    const int t = threadIdx.x;
    if (u < PREP_CVT) {
        int i = u * 256 + t;
        const float* src; int off;
        if (i < CVT_N1)      { src = qkv_w; off = i; }
        else if (i < CVT_N2) { src = o_w;   off = i - CVT_N1; }
        else if (i < CVT_N3) { src = w1;    off = i - CVT_N2; }
        else                 { src = w2;    off = i - CVT_N3; }
        float4 v = ((const float4*)src)[off];
        ushort4 o;
        o.x = f2bf_rne(v.x); o.y = f2bf_rne(v.y);
        o.z = f2bf_rne(v.z); o.w = f2bf_rne(v.w);
        ((ushort4*)wdst)[i] = o;
        return;
    }
    if (u < PREP_CVT + BB * SS) {
        int tid = (u - PREP_CVT) * 256 + t;
        int l15 = tid & 15;
        int kt  = (tid >> 4) & 15;
        int q   = (tid >> 8) & (SS - 1);
        int bb  = tid >> 18;
        const int* rrow = rel + ((size_t)(bb * SS + q)) * SS + kt * 64 + l15;
        const uchar_t* mrow = mask + (size_t)bb * SS + kt * 64 + l15;
        unsigned o = 0;
#pragma unroll
        for (int nt = 0; nt < 4; ++nt) {
            unsigned c = mrow[nt * 16] ? 3u : (unsigned)(rrow[nt * 16] + 1);
            o |= c << (8 * nt);
        }
        codes[((size_t)(bb * SS + q) * 16 + kt) * 16 + l15] = o;
        return;
    }
    // ---- LN1 row ----
    const int row = u - PREP_CVT - BB * SS;
    const float* xr = x + (size_t)row * DD;
    float s = 0.f, ss = 0.f;
    for (int i = t; i < DD; i += 256) {
        float v = xr[i];
        s += v; ss += v * v;
    }
    for (int off = 32; off; off >>= 1) {
        s  += __shfl_down(s,  off);
        ss += __shfl_down(ss, off);
    }
    if ((t & 63) == 0) { sm.r.reds[t >> 6] = s; sm.r.redss[t >> 6] = ss; }
    __syncthreads();
    if (t == 0) {
        float S1 = sm.r.reds[0] + sm.r.reds[1] + sm.r.reds[2] + sm.r.reds[3];
        float S2 = sm.r.redss[0] + sm.r.redss[1] + sm.r.redss[2] + sm.r.redss[3];
        float mean = S1 / DD;
        float var = S2 / DD - mean * mean;
        sm.r.bc[0] = mean;
        sm.r.bc[1] = rsqrtf(var + EPS);
    }
    __syncthreads();
    float mean = sm.r.bc[0], inv = sm.r.bc[1];
    ushort_t* yr = y + (size_t)row * DD;
    for (int i = t; i < DD; i += 256) {
        yr[i] = f2bf_rne((xr[i] - mean) * inv * g[i] + b[i]);
    }
}

// ---------------------------------------------------------------------------
// LDS double-buffered MFMA GEMM (R10 core), 64x128 tile, BK=64, 4 waves.
// tile id -> (n-block, m-block, z); nx = N/128, M/64 = 32 fixed.
// ---------------------------------------------------------------------------
template <bool RELU, bool OUT_BF16, bool HAS_BIAS, bool PARTIAL>
__device__ void gemm_dev(SMem& sm, int tile, int nx,
    const ushort_t* __restrict__ A, const ushort_t* __restrict__ W,
    const float* __restrict__ bias, void* __restrict__ Cout,
    int M, int N, int K, int Ksplit)
{
    const int t   = threadIdx.x;
    const int bxn = tile % nx;
    const int rem = tile / nx;
    const int bxm = rem & 31;
    const int bz  = rem >> 5;
    const int n0 = bxn * 128;
    const int m0 = bxm * 64;
    const int kb = bz * Ksplit;
    const int w  = t >> 6;
    const int l  = t & 63;
    const int wm = (w & 1) * 32;
    const int wn = (w >> 1) * 64;
    const int l15  = l & 15;
    const int quad = l >> 4;

    const ushort_t* gA = A + (size_t)(m0 + (t & 63)) * K + kb + (t >> 6) * 8;
    const ushort_t* gB = W + (size_t)(n0 + (t & 127)) * K + kb + (t >> 7) * 8;

    f32x4 acc[2][4] = {};

    {
        ushort_t* lA = &sm.g.As[0][(size_t)t * 8];
        ushort_t* lB = &sm.g.Bs[0][(size_t)t * 8];
        __builtin_amdgcn_global_load_lds(
            (const __attribute__((address_space(1))) unsigned int*)(gA),
            (__attribute__((address_space(3))) unsigned int*)lA, 16, 0, 0);
        __builtin_amdgcn_global_load_lds(
            (const __attribute__((address_space(1))) unsigned int*)(gA + 32),
            (__attribute__((address_space(3))) unsigned int*)(lA + 256 * 8), 16, 0, 0);
#pragma unroll
        for (int ii = 0; ii < 4; ++ii)
            __builtin_amdgcn_global_load_lds(
                (const __attribute__((address_space(1))) unsigned int*)(gB + ii * 16),
                (__attribute__((address_space(3))) unsigned int*)(lB + (size_t)ii * 256 * 8),
                16, 0, 0);
    }

    const int nIter = Ksplit >> 6;
    for (int it = 0; it < nIter; ++it) {
        __syncthreads();
        if (it + 1 < nIter) {
            const int k0 = (it + 1) << 6;
            const int nb = (it + 1) & 1;
            ushort_t* lA = &sm.g.As[nb][(size_t)t * 8];
            ushort_t* lB = &sm.g.Bs[nb][(size_t)t * 8];
            __builtin_amdgcn_global_load_lds(
                (const __attribute__((address_space(1))) unsigned int*)(gA + k0),
                (__attribute__((address_space(3))) unsigned int*)lA, 16, 0, 0);
            __builtin_amdgcn_global_load_lds(
                (const __attribute__((address_space(1))) unsigned int*)(gA + k0 + 32),
                (__attribute__((address_space(3))) unsigned int*)(lA + 256 * 8), 16, 0, 0);
#pragma unroll
            for (int ii = 0; ii < 4; ++ii)
                __builtin_amdgcn_global_load_lds(
                    (const __attribute__((address_space(1))) unsigned int*)(gB + k0 + ii * 16),
                    (__attribute__((address_space(3))) unsigned int*)(lB + (size_t)ii * 256 * 8),
                    16, 0, 0);
        }
        const int buf = it & 1;
#pragma unroll
        for (int ks = 0; ks < 2; ++ks) {
            const ushort_t* aptr = &sm.g.As[buf][(size_t)((ks * 4 + quad) * 64 + wm + l15) * 8];
            const ushort_t* bptr = &sm.g.Bs[buf][(size_t)((ks * 4 + quad) * 128 + wn + l15) * 8];
            short8 af[2], bf[4];
#pragma unroll
            for (int i = 0; i < 2; ++i)
                af[i] = *(const short8*)(aptr + (size_t)i * 16 * 8);
#pragma unroll
            for (int j = 0; j < 4; ++j)
                bf[j] = *(const short8*)(bptr + (size_t)j * 16 * 8);
#pragma unroll
            for (int i = 0; i < 2; ++i)
#pragma unroll
                for (int j = 0; j < 4; ++j)
                    acc[i][j] = __builtin_amdgcn_mfma_f32_16x16x32_bf16(
                        af[i], bf[j], acc[i][j], 0, 0, 0);
        }
    }

    if (PARTIAL) {
        ushort_t* Cp = (ushort_t*)Cout + (size_t)bz * ((size_t)M * N);
#pragma unroll
        for (int i = 0; i < 2; ++i) {
            const int row = m0 + wm + i * 16 + quad * 4;
#pragma unroll
            for (int j = 0; j < 4; ++j) {
                const int col = n0 + wn + j * 16 + l15;
#pragma unroll
                for (int r = 0; r < 4; ++r)
                    Cp[(size_t)(row + r) * N + col] = f2bf_rne(acc[i][j][r]);
            }
        }
    } else {
#pragma unroll
        for (int i = 0; i < 2; ++i) {
            const int row = m0 + wm + i * 16 + quad * 4;
#pragma unroll
            for (int j = 0; j < 4; ++j) {
                const int col = n0 + wn + j * 16 + l15;
                const float bv = HAS_BIAS ? bias[col] : 0.f;
#pragma unroll
                for (int r = 0; r < 4; ++r) {
                    float v = acc[i][j][r] + bv;
                    if (RELU) v = fmaxf(v, 0.f);
                    if (OUT_BF16)
                        ((ushort_t*)Cout)[(size_t)(row + r) * N + col] = f2bf_rne(v);
                    else
                        ((float*)Cout)[(size_t)(row + r) * N + col] = v;
                }
            }
        }
    }
}

// ---------------------------------------------------------------------------
// MFMA flash attention (R10 core), K-SPLIT x2, direct exp, dbuf staging.
// unit = (b, h, qtile, ks) linearized exactly as before; 768 units.
// ---------------------------------------------------------------------------
__device__ void attn_dev(SMem& sm, int unit,
    const ushort_t* __restrict__ qkv, const unsigned* __restrict__ codes,
    const float* __restrict__ rel_A, ushort_t* __restrict__ Opart,
    float* __restrict__ lpart)
{
    const int ks = unit & 1;
    const int qt = (unit >> 1) & 15;
    const int h  = (unit >> 5) % HH;
    const int b  = unit / (32 * HH);
    const int q0 = qt * 64;
    const int t  = threadIdx.x;
    const int w  = t >> 6;
    const int l  = t & 63;
    const int l15  = l & 15;
    const int quad = l >> 4;

    const int sr  = t >> 3;
    const int scp = t & 7;
    const int vkp = t >> 3;
    const int vdg = t & 7;
    const int vkps = vkp ^ (vdg * 4);

    const size_t qrow = (size_t)(b * SS + q0 + w * 16 + l15) * (3 * DD) + h * HD;
    const short8 qf0 = *(const short8*)(qkv + qrow + quad * 8);
    const short8 qf1 = *(const short8*)(qkv + qrow + 32 + quad * 8);

    {
        float rv[3];
#pragma unroll
        for (int c = 0; c < 3; ++c) {
            const float* a = rel_A + c * HD + quad * 8;
            float acc = 0.f;
#pragma unroll
            for (int j = 0; j < 8; ++j) acc += bf2f(qf0[j]) * a[j];
#pragma unroll
            for (int j = 0; j < 8; ++j) acc += bf2f(qf1[j]) * a[32 + j];
            acc += __shfl_xor(acc, 16);
            acc += __shfl_xor(acc, 32);
            rv[c] = acc;
        }
        if (quad == 0) {
            float4 f4 = make_float4(rv[0], rv[1], rv[2], -2.4e31f);
            *(float4*)&sm.a.r3s[w * 16 + l15][0] = f4;
        }
    }

    float l_run[4] = {0.f, 0.f, 0.f, 0.f};
    f32x4 oacc[4] = {};

    const int kt0 = ks * 8;
    short8 va, vb;
    {
        const int k0 = kt0 * 64;
        const int cl  = scp ^ (sr & 7);
        const ushort_t* g = qkv + (size_t)(b * SS + k0 + sr) * (3 * DD) + DD + h * HD + cl * 8;
        __builtin_amdgcn_global_load_lds(
            (const __attribute__((address_space(1))) unsigned*)g,
            (__attribute__((address_space(3))) unsigned*)(&sm.a.Ks[0][0] + (size_t)t * 8), 16, 0, 0);
        const int r2  = sr + 32;
        const int cl2 = scp ^ (r2 & 7);
        const ushort_t* g2 = qkv + (size_t)(b * SS + k0 + r2) * (3 * DD) + DD + h * HD + cl2 * 8;
        __builtin_amdgcn_global_load_lds(
            (const __attribute__((address_space(1))) unsigned*)g2,
            (__attribute__((address_space(3))) unsigned*)(&sm.a.Ks[0][0] + (size_t)(t + 256) * 8), 16, 0, 0);
        const ushort_t* gv = qkv + (size_t)(b * SS + k0 + 2 * vkp) * (3 * DD) + 2 * DD + h * HD + vdg * 8;
        va = *(const short8*)gv;
        vb = *(const short8*)(gv + 3 * DD);
#pragma unroll
        for (int i = 0; i < 8; ++i)
            sm.a.Vt2[0][(size_t)(vdg * 8 + i) * 36 + vkps] =
                (unsigned)(ushort_t)va[i] | ((unsigned)(ushort_t)vb[i] << 16);
    }
    __syncthreads();
    float4 r3v[4];
#pragma unroll
    for (int reg = 0; reg < 4; ++reg)
        r3v[reg] = *(const float4*)&sm.a.r3s[w * 16 + quad * 4 + reg][0];

    for (int i8 = 0; i8 < 8; ++i8) {
        const int kt  = kt0 + i8;
        const int cur = i8 & 1;
        const bool more = (i8 + 1 < 8);
        if (more) {
            const int k0 = (kt + 1) * 64;
            const int nb = cur ^ 1;
            const int cl  = scp ^ (sr & 7);
            const ushort_t* g = qkv + (size_t)(b * SS + k0 + sr) * (3 * DD) + DD + h * HD + cl * 8;
            __builtin_amdgcn_global_load_lds(
                (const __attribute__((address_space(1))) unsigned*)g,
                (__attribute__((address_space(3))) unsigned*)(&sm.a.Ks[nb][0] + (size_t)t * 8), 16, 0, 0);
            const int r2  = sr + 32;
            const int cl2 = scp ^ (r2 & 7);
            const ushort_t* g2 = qkv + (size_t)(b * SS + k0 + r2) * (3 * DD) + DD + h * HD + cl2 * 8;
            __builtin_amdgcn_global_load_lds(
                (const __attribute__((address_space(1))) unsigned*)g2,
                (__attribute__((address_space(3))) unsigned*)(&sm.a.Ks[nb][0] + (size_t)(t + 256) * 8), 16, 0, 0);
            const ushort_t* gv = qkv + (size_t)(b * SS + k0 + 2 * vkp) * (3 * DD) + 2 * DD + h * HD + vdg * 8;
            va = *(const short8*)gv;
            vb = *(const short8*)(gv + 3 * DD);
        }

        f32x4 sacc[4] = {};
#pragma unroll
        for (int kc = 0; kc < 2; ++kc) {
            const short8 qv = kc ? qf1 : qf0;
#pragma unroll
            for (int nt = 0; nt < 4; ++nt) {
                const int row = nt * 16 + l15;
                const int cp  = (kc * 4 + quad) ^ (row & 7);
                const short8 kf = *(const short8*)(&sm.a.Ks[cur][0] + (size_t)row * 64 + cp * 8);
                sacc[nt] = __builtin_amdgcn_mfma_f32_16x16x32_bf16(qv, kf, sacc[nt], 0, 0, 0);
            }
        }

#pragma unroll
        for (int reg = 0; reg < 4; ++reg) {
            const int qloc = w * 16 + quad * 4 + reg;
            const unsigned cds = codes[((size_t)(b * SS + q0 + qloc) * 16 + kt) * 16 + l15];
            const float4 r4 = r3v[reg];
#pragma unroll
            for (int nt = 0; nt < 4; ++nt) {
                const unsigned c = (cds >> (8 * nt)) & 0xff;
                float rvv = (c == 0) ? r4.x : (c == 1) ? r4.y : (c == 2) ? r4.z : r4.w;
                const float p = __expf((sacc[nt][reg] + rvv) * 0.125f);
                l_run[reg] += p;
                sm.a.Ps[(size_t)qloc * 72 + nt * 16 + l15] = f2bf_rne(p);
            }
        }

#pragma unroll
        for (int kc = 0; kc < 2; ++kc) {
            const short8 pf = *(const short8*)(sm.a.Ps + (size_t)(w * 16 + l15) * 72 + kc * 32 + quad * 8);
#pragma unroll
            for (int dt = 0; dt < 4; ++dt) {
                const int d  = dt * 16 + l15;
                const int dg = d >> 3;
                const int kps0 = (kc * 16 + quad * 4) ^ ((dg & 7) * 4);
                const short8 vf = *(const short8*)((const ushort_t*)&sm.a.Vt2[cur][(size_t)d * 36 + kps0]);
                oacc[dt] = __builtin_amdgcn_mfma_f32_16x16x32_bf16(pf, vf, oacc[dt], 0, 0, 0);
            }
        }

        if (more) {
            const int nb = cur ^ 1;
#pragma unroll
            for (int i = 0; i < 8; ++i)
                sm.a.Vt2[nb][(size_t)(vdg * 8 + i) * 36 + vkps] =
                    (unsigned)(ushort_t)va[i] | ((unsigned)(ushort_t)vb[i] << 16);
            __syncthreads();
        }
    }

    ushort_t* Op = Opart + (size_t)ks * BSD;
    float* lp = lpart + (size_t)ks * BS2 * HH;
#pragma unroll
    for (int reg = 0; reg < 4; ++reg) {
        float ls = l_run[reg];
        ls += __shfl_xor(ls, 1);
        ls += __shfl_xor(ls, 2);
        ls += __shfl_xor(ls, 4);
        ls += __shfl_xor(ls, 8);
        const int orow = b * SS + q0 + w * 16 + quad * 4 + reg;
#pragma unroll
        for (int dt = 0; dt < 4; ++dt)
            Op[(size_t)orow * DD + h * HD + dt * 16 + l15] = f2bf_rne(oacc[dt][reg]);
        if (l15 == 0) lp[(size_t)orow * HH + h] = ls;
    }
}

// ---------------------------------------------------------------------------
// merge2 + LN2 for one row
// ---------------------------------------------------------------------------
__device__ void merge2ln_row(SMem& sm, int row,
    const ushort_t* __restrict__ part, const float* __restrict__ inp,
    const float* __restrict__ g, const float* __restrict__ b,
    float* __restrict__ resid, ushort_t* __restrict__ h_bf)
{
    const int t = threadIdx.x;
    float4 v = make_float4(0.f, 0.f, 0.f, 0.f);
    const size_t idx = (size_t)row * (DD / 4) + t;
    if (t < DD / 4) {
        v = ((const float4*)inp)[idx];
        ushort4 p0 = ((const ushort4*)part)[idx];
        ushort4 p1 = ((const ushort4*)(part + BSD))[idx];
        v.x += bf2f(p0.x) + bf2f(p1.x);
        v.y += bf2f(p0.y) + bf2f(p1.y);
        v.z += bf2f(p0.z) + bf2f(p1.z);
        v.w += bf2f(p0.w) + bf2f(p1.w);
        ((float4*)resid)[idx] = v;
    }
    float s  = v.x + v.y + v.z + v.w;
    float ss = v.x * v.x + v.y * v.y + v.z * v.z + v.w * v.w;
    for (int off = 32; off; off >>= 1) {
        s  += __shfl_down(s,  off);
        ss += __shfl_down(ss, off);
    }
    if ((t & 63) == 0) { sm.r.reds[t >> 6] = s; sm.r.redss[t >> 6] = ss; }
    __syncthreads();
    if (t == 0) {
        float S1 = sm.r.reds[0] + sm.r.reds[1] + sm.r.reds[2] + sm.r.reds[3];
        float S2 = sm.r.redss[0] + sm.r.redss[1] + sm.r.redss[2] + sm.r.redss[3];
        float mean = S1 / DD;
        float var = S2 / DD - mean * mean;
        sm.r.bc[0] = mean;
        sm.r.bc[1] = rsqrtf(var + EPS);
    }
    __syncthreads();
    if (t < DD / 4) {
        const float mean = sm.r.bc[0], inv = sm.r.bc[1];
        float4 gv = ((const float4*)g)[t];
        float4 bv = ((const float4*)b)[t];
        ushort4 o;
        o.x = f2bf_rne((v.x - mean) * inv * gv.x + bv.x);
        o.y = f2bf_rne((v.y - mean) * inv * gv.y + bv.y);
        o.z = f2bf_rne((v.z - mean) * inv * gv.z + bv.z);
        o.w = f2bf_rne((v.w - mean) * inv * gv.w + bv.w);
        ((ushort4*)h_bf)[idx] = o;
    }
}

// ---------------------------------------------------------------------------
// MEGA KERNEL: all phases, grid = 768 x 256, hand-rolled grid barriers.
// ---------------------------------------------------------------------------
__global__ __launch_bounds__(256, 3) void mega_kernel(
    const float* inp, const uchar_t* amask, const int* relm,
    const float* qkv_w, const float* rel_A, const float* o_w,
    const float* w1, const float* b1, const float* w2, const float* b2,
    const float* ln1_g, const float* ln1_b, const float* ln2_g, const float* ln2_b,
    float* out, char* ws, unsigned* bar)
{
    __shared__ SMem sm;
    const int bx = blockIdx.x;
    const int t  = threadIdx.x;

    // workspace layout (must match host)
    char* p = ws;
    ushort_t* x_bf   = (ushort_t*)p; p += BSD * 2;
    ushort_t* att_bf = (ushort_t*)p; p += BSD * 2;
    ushort_t* h_bf   = (ushort_t*)p; p += BSD * 2;
    ushort_t* ff_bf  = (ushort_t*)p; p += (size_t)BS2 * DFF * 2;
    ushort_t* qkvw_bf= (ushort_t*)p; p += (size_t)3 * DD * DD * 2;
    ushort_t* ow_bf  = (ushort_t*)p; p += (size_t)DD * DD * 2;
    ushort_t* w1_bf  = (ushort_t*)p; p += (size_t)DFF * DD * 2;
    ushort_t* w2_bf  = (ushort_t*)p; p += (size_t)DD * DFF * 2;
    ushort_t* qkv_bf = (ushort_t*)p; p += (size_t)BS2 * 3 * DD * 2;
    float*    resid  = (float*)p;    p += BSD * 4;
    ushort_t* pool   = (ushort_t*)p; p += 4 * BSD * 2;
    ushort_t* Opart  = (ushort_t*)p; p += 2 * BSD * 2;
    float*    lpart  = (float*)p;    p += (size_t)2 * BS2 * HH * 4;
    unsigned* codes  = (unsigned*)p; p += (size_t)BB * SS * SS;

    unsigned* cnt = bar;
    unsigned* gen = bar + 16;   // separate cachelines

    // ---- phase 0: prep (cvt + codes + LN1) ----
    for (int u = bx; u < PREP_TOT; u += GB) {
        prep_unit(sm, u, qkv_w, o_w, w1, w2, qkvw_bf, relm, amask, codes,
                  inp, ln1_g, ln1_b, x_bf);
        __syncthreads();
    }
    grid_barrier(cnt, gen);

    // ---- phase 1: QKV (576 tiles) ----
    if (bx < 576)
        gemm_dev<false, true, false, false>(sm, bx, 18,
            x_bf, qkvw_bf, nullptr, qkv_bf, BS2, 3 * DD, DD, DD);
    grid_barrier(cnt, gen);

    // ---- phase 2: attention (768 units) ----
    attn_dev(sm, bx, qkv_bf, codes, rel_A, Opart, lpart);
    grid_barrier(cnt, gen);

    // ---- phase 3: attn merge (grid-stride, 2 float4 per thread) ----
    {
        const int n4 = (int)(BSD / 4);
        for (int i = bx * 256 + t; i < n4; i += GB * 256) {
            int row = (i * 4) / DD;
            int h   = ((i * 4) % DD) >> 6;
            float l0 = lpart[(size_t)row * HH + h];
            float l1 = lpart[(size_t)BS2 * HH + (size_t)row * HH + h];
            float inv = 1.0f / (l0 + l1);
            ushort4 a = ((const ushort4*)Opart)[i];
            ushort4 b = ((const ushort4*)(Opart + BSD))[i];
            ushort4 o;
            o.x = f2bf_rne((bf2f(a.x) + bf2f(b.x)) * inv);
            o.y = f2bf_rne((bf2f(a.y) + bf2f(b.y)) * inv);
            o.z = f2bf_rne((bf2f(a.z) + bf2f(b.z)) * inv);
            o.w = f2bf_rne((bf2f(a.w) + bf2f(b.w)) * inv);
            ((ushort4*)att_bf)[i] = o;
        }
    }
    grid_barrier(cnt, gen);

    // ---- phase 4: o-proj partials (384 tiles, Z=2) ----
    if (bx < 384)
        gemm_dev<false, false, false, true>(sm, bx, 6,
            att_bf, ow_bf, nullptr, pool, BS2, DD, DD, DD / 2);
    grid_barrier(cnt, gen);

    // ---- phase 5: merge2 + LN2 (2048 rows) ----
    for (int r = bx; r < BS2; r += GB) {
        merge2ln_row(sm, r, pool, inp, ln2_g, ln2_b, resid, h_bf);
        __syncthreads();
    }
    grid_barrier(cnt, gen);

    // ---- phase 6: MLP1 (768 tiles) ----
    gemm_dev<true, true, true, false>(sm, bx, 24,
        h_bf, w1_bf, b1, ff_bf, BS2, DFF, DD, DD);
    grid_barrier(cnt, gen);

    // ---- phase 7: MLP2 partials (768 tiles, Z=4) ----
    gemm_dev<false, false, false, true>(sm, bx, 6,
        ff_bf, w2_bf, nullptr, pool, BS2, DD, DFF, DFF / 4);
    grid_barrier(cnt, gen);

    // ---- phase 8: final merge4 ----
    {
        const int n4 = (int)(BSD / 4);
        for (int i = bx * 256 + t; i < n4; i += GB * 256) {
            float4 v = ((const float4*)resid)[i];
            int col4 = (i * 4) % DD;
            float4 bv = *(const float4*)(b2 + col4);
            v.x += bv.x; v.y += bv.y; v.z += bv.z; v.w += bv.w;
#pragma unroll
            for (int z = 0; z < 4; ++z) {
                ushort4 pz = ((const ushort4*)(pool + (size_t)z * BSD))[i];
                v.x += bf2f(pz.x); v.y += bf2f(pz.y);
                v.z += bf2f(pz.z); v.w += bf2f(pz.w);
            }
            ((float4*)out)[i] = v;
        }
    }
}

// ---------------------------------------------------------------------------
extern "C" void kernel_launch(void* const* d_in, const int* in_sizes, int n_in,
                              void* d_out, int out_size, void* d_ws, size_t ws_size,
                              hipStream_t stream) {
    const float* inp   = (const float*)d_in[0];
    const uchar_t* amask = (const uchar_t*)d_in[1];
    const int*   relm  = (const int*)d_in[2];
    const float* qkv_w = (const float*)d_in[3];
    const float* rel_A = (const float*)d_in[4];
    const float* o_w   = (const float*)d_in[5];
    const float* w1    = (const float*)d_in[6];
    const float* b1    = (const float*)d_in[7];
    const float* w2    = (const float*)d_in[8];
    const float* b2    = (const float*)d_in[9];
    const float* ln1_g = (const float*)d_in[10];
    const float* ln1_b = (const float*)d_in[11];
    const float* ln2_g = (const float*)d_in[12];
    const float* ln2_b = (const float*)d_in[13];
    float* out = (float*)d_out;

    // barrier state at the far end of the workspace (zeroed every call)
    size_t data_bytes =
        BSD * 2 * 3 + (size_t)BS2 * DFF * 2 + (size_t)3 * DD * DD * 2 +
        (size_t)DD * DD * 2 + (size_t)DFF * DD * 2 * 2 +
        (size_t)BS2 * 3 * DD * 2 + BSD * 4 + 4 * BSD * 2 + 2 * BSD * 2 +
        (size_t)2 * BS2 * HH * 4 + (size_t)BB * SS * SS * 4;
    (void)data_bytes;
    unsigned* bar = (unsigned*)((char*)d_ws + ws_size - 256);
    hipMemsetAsync(bar, 0, 256, stream);

    mega_kernel<<<GB, 256, 0, stream>>>(
        inp, amask, relm, qkv_w, rel_A, o_w, w1, b1, w2, b2,
        ln1_g, ln1_b, ln2_g, ln2_b, out, (char*)d_ws, bar);
}

// Round 12
// 257.410 us; speedup vs baseline: 8.3834x; 8.3834x over previous
//
#include <hip/hip_runtime.h>
#include <hip/hip_bf16.h>

// Problem constants
#define BB 2
#define SS 1024
#define DD 768
#define HH 12
#define HD 64
#define DFF 3072
#define EPS 1e-5f
#define BS2 (BB * SS)            // 2048
#define BSD ((size_t)BS2 * DD)   // 2048*768

typedef unsigned short ushort_t;
typedef unsigned char uchar_t;
using short8 = __attribute__((ext_vector_type(8))) short;
using f32x4  = __attribute__((ext_vector_type(4))) float;

// s_waitcnt immediates (gfx9 encoding): vmcnt[3:0]|expcnt<<4|lgkmcnt<<8|vmcnt[5:4]<<14
#define WAITCNT_LGKM0 0xC07F     // lgkmcnt(0), vmcnt/expcnt unconstrained

__device__ __forceinline__ ushort_t f2bf_rne(float f) {
    union { float f; unsigned u; } x; x.f = f;
    unsigned r = x.u + 0x7fff + ((x.u >> 16) & 1);
    return (ushort_t)(r >> 16);
}
__device__ __forceinline__ float bf2f(short u) {
    union { unsigned i; float f; } x;
    x.i = ((unsigned)(ushort_t)u) << 16;
    return x.f;
}

// ---------------------------------------------------------------------------
// prep kernel: ONE launch does (a) fp32->bf16 weight conversion, (b) rel/mask
// code packing, (c) LN1. Disjoint blockIdx ranges.
// ---------------------------------------------------------------------------
#define CVT_N1 (3 * DD * DD / 4)
#define CVT_N2 (CVT_N1 + DD * DD / 4)
#define CVT_N3 (CVT_N2 + DFF * DD / 4)
#define CVT_NT (CVT_N3 + DD * DFF / 4)
#define PREP_CVT   (CVT_NT / 256)
#define PREP_CODES (BB * SS)
#define PREP_LN    BS2

__global__ __launch_bounds__(256) void prep_kernel(
    const float* __restrict__ qkv_w, const float* __restrict__ o_w,
    const float* __restrict__ w1, const float* __restrict__ w2,
    ushort_t* __restrict__ wdst,
    const int* __restrict__ rel, const uchar_t* __restrict__ mask,
    unsigned* __restrict__ codes,
    const float* __restrict__ x, const float* __restrict__ g,
    const float* __restrict__ b, ushort_t* __restrict__ y)
{
    const int bx = blockIdx.x;
    const int t  = threadIdx.x;
    if (bx < PREP_CVT) {
        int i = bx * 256 + t;
        const float* src; int off;
        if (i < CVT_N1)      { src = qkv_w; off = i; }
        else if (i < CVT_N2) { src = o_w;   off = i - CVT_N1; }
        else if (i < CVT_N3) { src = w1;    off = i - CVT_N2; }
        else                 { src = w2;    off = i - CVT_N3; }
        float4 v = ((const float4*)src)[off];
        ushort4 o;
        o.x = f2bf_rne(v.x); o.y = f2bf_rne(v.y);
        o.z = f2bf_rne(v.z); o.w = f2bf_rne(v.w);
        ((ushort4*)wdst)[i] = o;
        return;
    }
    if (bx < PREP_CVT + PREP_CODES) {
        int tid = (bx - PREP_CVT) * 256 + t;
        int l15 = tid & 15;
        int kt  = (tid >> 4) & 15;
        int q   = (tid >> 8) & (SS - 1);
        int bb  = tid >> 18;
        const int* rrow = rel + ((size_t)(bb * SS + q)) * SS + kt * 64 + l15;
        const uchar_t* mrow = mask + (size_t)bb * SS + kt * 64 + l15;
        unsigned o = 0;
#pragma unroll
        for (int nt = 0; nt < 4; ++nt) {
            unsigned c = mrow[nt * 16] ? 3u : (unsigned)(rrow[nt * 16] + 1);
            o |= c << (8 * nt);
        }
        codes[((size_t)(bb * SS + q) * 16 + kt) * 16 + l15] = o;
        return;
    }
    // ---- LN1 ----
    const int row = bx - PREP_CVT - PREP_CODES;
    const float* xr = x + (size_t)row * DD;
    float s = 0.f, ss = 0.f;
    for (int i = t; i < DD; i += 256) {
        float v = xr[i];
        s += v; ss += v * v;
    }
    for (int off = 32; off; off >>= 1) {
        s  += __shfl_down(s,  off);
        ss += __shfl_down(ss, off);
    }
    __shared__ float reds[4], redss[4], bc[2];
    if ((t & 63) == 0) { reds[t >> 6] = s; redss[t >> 6] = ss; }
    __syncthreads();
    if (t == 0) {
        float S1 = reds[0] + reds[1] + reds[2] + reds[3];
        float S2 = redss[0] + redss[1] + redss[2] + redss[3];
        float mean = S1 / DD;
        float var = S2 / DD - mean * mean;
        bc[0] = mean;
        bc[1] = rsqrtf(var + EPS);
    }
    __syncthreads();
    float mean = bc[0], inv = bc[1];
    ushort_t* yr = y + (size_t)row * DD;
    for (int i = t; i < DD; i += 256) {
        yr[i] = f2bf_rne((xr[i] - mean) * inv * g[i] + b[i]);
    }
}

// ---------------------------------------------------------------------------
// Fused: resid = inp + p0 + p1 (bf16 partials) ; h_bf = LN(resid).
// ---------------------------------------------------------------------------
__global__ __launch_bounds__(256) void merge2_ln_kernel(
    const ushort_t* __restrict__ part, const float* __restrict__ inp,
    const float* __restrict__ g, const float* __restrict__ b,
    float* __restrict__ resid, ushort_t* __restrict__ h_bf)
{
    const int row = blockIdx.x;
    const int t = threadIdx.x;
    float4 v = make_float4(0.f, 0.f, 0.f, 0.f);
    const size_t idx = (size_t)row * (DD / 4) + t;
    if (t < DD / 4) {
        v = ((const float4*)inp)[idx];
        ushort4 p0 = ((const ushort4*)part)[idx];
        ushort4 p1 = ((const ushort4*)(part + BSD))[idx];
        v.x += bf2f(p0.x) + bf2f(p1.x);
        v.y += bf2f(p0.y) + bf2f(p1.y);
        v.z += bf2f(p0.z) + bf2f(p1.z);
        v.w += bf2f(p0.w) + bf2f(p1.w);
        ((float4*)resid)[idx] = v;
    }
    float s  = v.x + v.y + v.z + v.w;
    float ss = v.x * v.x + v.y * v.y + v.z * v.z + v.w * v.w;
    for (int off = 32; off; off >>= 1) {
        s  += __shfl_down(s,  off);
        ss += __shfl_down(ss, off);
    }
    __shared__ float reds[4], redss[4], bc[2];
    if ((t & 63) == 0) { reds[t >> 6] = s; redss[t >> 6] = ss; }
    __syncthreads();
    if (t == 0) {
        float S1 = reds[0] + reds[1] + reds[2] + reds[3];
        float S2 = redss[0] + redss[1] + redss[2] + redss[3];
        float mean = S1 / DD;
        float var = S2 / DD - mean * mean;
        bc[0] = mean;
        bc[1] = rsqrtf(var + EPS);
    }
    __syncthreads();
    if (t < DD / 4) {
        const float mean = bc[0], inv = bc[1];
        float4 gv = ((const float4*)g)[t];
        float4 bv = ((const float4*)b)[t];
        ushort4 o;
        o.x = f2bf_rne((v.x - mean) * inv * gv.x + bv.x);
        o.y = f2bf_rne((v.y - mean) * inv * gv.y + bv.y);
        o.z = f2bf_rne((v.z - mean) * inv * gv.z + bv.z);
        o.w = f2bf_rne((v.w - mean) * inv * gv.w + bv.w);
        ((ushort4*)h_bf)[idx] = o;
    }
}

// ---------------------------------------------------------------------------
// merge4: out = resid + b2 + sum of 4 bf16 partial slices.
// ---------------------------------------------------------------------------
__global__ __launch_bounds__(256) void merge4_kernel(
    const ushort_t* __restrict__ part, const float* __restrict__ resid,
    const float* __restrict__ b2, float* __restrict__ outp, int n4)
{
    int i = blockIdx.x * 256 + threadIdx.x;
    if (i >= n4) return;
    float4 v = ((const float4*)resid)[i];
    int col4 = (i * 4) % DD;
    float4 bv = *(const float4*)(b2 + col4);
    v.x += bv.x; v.y += bv.y; v.z += bv.z; v.w += bv.w;
#pragma unroll
    for (int z = 0; z < 4; ++z) {
        ushort4 pz = ((const ushort4*)(part + (size_t)z * BSD))[i];
        v.x += bf2f(pz.x); v.y += bf2f(pz.y);
        v.z += bf2f(pz.z); v.w += bf2f(pz.w);
    }
    ((float4*)outp)[i] = v;
}

// ---------------------------------------------------------------------------
// REGISTER-PIPELINED MFMA GEMM, 64x128 tile, BK=64, 256 threads = 4 waves.
// Staging: plain global loads -> VGPRs (6 short8/thread); ds_write after a
// raw s_barrier. The vmcnt wait for staged regs is inserted by the compiler
// at the ds_write use-site — i.e. AFTER a full compute phase in flight.
// NO vmcnt(0) anywhere in the loop: barriers are raw s_barrier with explicit
// lgkmcnt(0) only. Single 24 KB LDS buffer (two light barriers/iter).
// grid = (N/128, M/64, Z); Ksplit = K/Z (divisible by 64).
// ---------------------------------------------------------------------------
template <bool RELU, bool OUT_BF16, bool HAS_BIAS, bool PARTIAL>
__global__ __launch_bounds__(256) void gemm_tile(
    const ushort_t* __restrict__ A, const ushort_t* __restrict__ W,
    const float* __restrict__ bias, void* __restrict__ Cout,
    int M, int N, int K, int Ksplit)
{
    __shared__ __align__(16) ushort_t As[512 * 8];    // 8 KB  (64 rows x 8 kq)
    __shared__ __align__(16) ushort_t Bs[1024 * 8];   // 16 KB (128 rows x 8 kq)

    const int t  = threadIdx.x;
    const int n0 = blockIdx.x * 128;
    const int m0 = blockIdx.y * 64;
    const int kb = blockIdx.z * Ksplit;
    const int w  = t >> 6;
    const int l  = t & 63;
    const int wm = (w & 1) * 32;
    const int wn = (w >> 1) * 64;
    const int l15  = l & 15;
    const int quad = l >> 4;

    // A: thread covers slots t (kq=t>>6, row=t&63) and t+256 (kq+4)
    const ushort_t* gA = A + (size_t)(m0 + (t & 63)) * K + kb + (t >> 6) * 8;
    // B: thread covers slots t+256*ii (kq=(t>>7)+2*ii, row=t&127)
    const ushort_t* gB = W + (size_t)(n0 + (t & 127)) * K + kb + (t >> 7) * 8;

    // prologue: stage tile 0 into registers
    short8 pa0 = *(const short8*)(gA);
    short8 pa1 = *(const short8*)(gA + 32);
    short8 pb0 = *(const short8*)(gB);
    short8 pb1 = *(const short8*)(gB + 16);
    short8 pb2 = *(const short8*)(gB + 32);
    short8 pb3 = *(const short8*)(gB + 48);

    f32x4 acc[2][4] = {};
    const int nIter = Ksplit >> 6;

    for (int it = 0; it < nIter; ++it) {
        // barrier A: all waves finished reading LDS from the previous iter
        __builtin_amdgcn_s_barrier();
        // commit staged tile to LDS (compiler inserts precise vmcnt waits here)
        *(short8*)&As[(size_t)t * 8]           = pa0;
        *(short8*)&As[(size_t)(t + 256) * 8]   = pa1;
        *(short8*)&Bs[(size_t)t * 8]           = pb0;
        *(short8*)&Bs[(size_t)(t + 256) * 8]   = pb1;
        *(short8*)&Bs[(size_t)(t + 512) * 8]   = pb2;
        *(short8*)&Bs[(size_t)(t + 768) * 8]   = pb3;
        // issue next tile's loads (in flight across the whole compute phase)
        if (it + 1 < nIter) {
            const int k0 = (it + 1) << 6;
            pa0 = *(const short8*)(gA + k0);
            pa1 = *(const short8*)(gA + k0 + 32);
            pb0 = *(const short8*)(gB + k0);
            pb1 = *(const short8*)(gB + k0 + 16);
            pb2 = *(const short8*)(gB + k0 + 32);
            pb3 = *(const short8*)(gB + k0 + 48);
        }
        // my ds_writes done; barrier B: everyone's writes visible
        __builtin_amdgcn_s_waitcnt(WAITCNT_LGKM0);
        __builtin_amdgcn_s_barrier();

#pragma unroll
        for (int ks = 0; ks < 2; ++ks) {
            const ushort_t* aptr = &As[(size_t)((ks * 4 + quad) * 64 + wm + l15) * 8];
            const ushort_t* bptr = &Bs[(size_t)((ks * 4 + quad) * 128 + wn + l15) * 8];
            short8 af[2], bf[4];
#pragma unroll
            for (int i = 0; i < 2; ++i)
                af[i] = *(const short8*)(aptr + (size_t)i * 16 * 8);
#pragma unroll
            for (int j = 0; j < 4; ++j)
                bf[j] = *(const short8*)(bptr + (size_t)j * 16 * 8);
#pragma unroll
            for (int i = 0; i < 2; ++i)
#pragma unroll
                for (int j = 0; j < 4; ++j)
                    acc[i][j] = __builtin_amdgcn_mfma_f32_16x16x32_bf16(
                        af[i], bf[j], acc[i][j], 0, 0, 0);
        }
    }

    // epilogue: C/D layout col=lane&15, row=(lane>>4)*4+reg
    if (PARTIAL) {
        ushort_t* Cp = (ushort_t*)Cout + (size_t)blockIdx.z * ((size_t)M * N);
#pragma unroll
        for (int i = 0; i < 2; ++i) {
            const int row = m0 + wm + i * 16 + quad * 4;
#pragma unroll
            for (int j = 0; j < 4; ++j) {
                const int col = n0 + wn + j * 16 + l15;
#pragma unroll
                for (int r = 0; r < 4; ++r)
                    Cp[(size_t)(row + r) * N + col] = f2bf_rne(acc[i][j][r]);
            }
        }
    } else {
#pragma unroll
        for (int i = 0; i < 2; ++i) {
            const int row = m0 + wm + i * 16 + quad * 4;
#pragma unroll
            for (int j = 0; j < 4; ++j) {
                const int col = n0 + wn + j * 16 + l15;
                const float bv = HAS_BIAS ? bias[col] : 0.f;
#pragma unroll
                for (int r = 0; r < 4; ++r) {
                    float v = acc[i][j][r] + bv;
                    if (RELU) v = fmaxf(v, 0.f);
                    if (OUT_BF16)
                        ((ushort_t*)Cout)[(size_t)(row + r) * N + col] = f2bf_rne(v);
                    else
                        ((float*)Cout)[(size_t)(row + r) * N + col] = v;
                }
            }
        }
    }
}

// ---------------------------------------------------------------------------
// MFMA flash attention (R10 core, unchanged), K-SPLIT x2, direct exp, dbuf.
// Block per (b, h, qtile, ks): grid = 768.
// ---------------------------------------------------------------------------
__global__ __launch_bounds__(256) void attn_mfma_kernel(
    const ushort_t* __restrict__ qkv,
    const unsigned* __restrict__ codes,
    const float* __restrict__ rel_A,
    ushort_t* __restrict__ Opart,
    float* __restrict__ lpart)
{
    __shared__ __align__(16) ushort_t Ks[2][64 * 64];
    __shared__ __align__(16) unsigned Vt2[2][64 * 36];
    __shared__ __align__(16) ushort_t Ps[64 * 72];
    __shared__ __align__(16) float r3s[64][4];

    const int bx = blockIdx.x;
    const int ks = bx & 1;
    const int qt = (bx >> 1) & 15;
    const int h  = (bx >> 5) % HH;
    const int b  = bx / (32 * HH);
    const int q0 = qt * 64;
    const int t  = threadIdx.x;
    const int w  = t >> 6;
    const int l  = t & 63;
    const int l15  = l & 15;
    const int quad = l >> 4;

    const int sr  = t >> 3;
    const int scp = t & 7;
    const int vkp = t >> 3;
    const int vdg = t & 7;
    const int vkps = vkp ^ (vdg * 4);

    const size_t qrow = (size_t)(b * SS + q0 + w * 16 + l15) * (3 * DD) + h * HD;
    const short8 qf0 = *(const short8*)(qkv + qrow + quad * 8);
    const short8 qf1 = *(const short8*)(qkv + qrow + 32 + quad * 8);

    {
        float rv[3];
#pragma unroll
        for (int c = 0; c < 3; ++c) {
            const float* a = rel_A + c * HD + quad * 8;
            float acc = 0.f;
#pragma unroll
            for (int j = 0; j < 8; ++j) acc += bf2f(qf0[j]) * a[j];
#pragma unroll
            for (int j = 0; j < 8; ++j) acc += bf2f(qf1[j]) * a[32 + j];
            acc += __shfl_xor(acc, 16);
            acc += __shfl_xor(acc, 32);
            rv[c] = acc;
        }
        if (quad == 0) {
            float4 f4 = make_float4(rv[0], rv[1], rv[2], -2.4e31f);
            *(float4*)&r3s[w * 16 + l15][0] = f4;
        }
    }

    float l_run[4] = {0.f, 0.f, 0.f, 0.f};
    f32x4 oacc[4] = {};

    const int kt0 = ks * 8;
    short8 va, vb;
    {
        const int k0 = kt0 * 64;
        const int cl  = scp ^ (sr & 7);
        const ushort_t* g = qkv + (size_t)(b * SS + k0 + sr) * (3 * DD) + DD + h * HD + cl * 8;
        __builtin_amdgcn_global_load_lds(
            (const __attribute__((address_space(1))) unsigned*)g,
            (__attribute__((address_space(3))) unsigned*)(&Ks[0][0] + (size_t)t * 8), 16, 0, 0);
        const int r2  = sr + 32;
        const int cl2 = scp ^ (r2 & 7);
        const ushort_t* g2 = qkv + (size_t)(b * SS + k0 + r2) * (3 * DD) + DD + h * HD + cl2 * 8;
        __builtin_amdgcn_global_load_lds(
            (const __attribute__((address_space(1))) unsigned*)g2,
            (__attribute__((address_space(3))) unsigned*)(&Ks[0][0] + (size_t)(t + 256) * 8), 16, 0, 0);
        const ushort_t* gv = qkv + (size_t)(b * SS + k0 + 2 * vkp) * (3 * DD) + 2 * DD + h * HD + vdg * 8;
        va = *(const short8*)gv;
        vb = *(const short8*)(gv + 3 * DD);
#pragma unroll
        for (int i = 0; i < 8; ++i)
            Vt2[0][(size_t)(vdg * 8 + i) * 36 + vkps] =
                (unsigned)(ushort_t)va[i] | ((unsigned)(ushort_t)vb[i] << 16);
    }
    __syncthreads();
    float4 r3v[4];
#pragma unroll
    for (int reg = 0; reg < 4; ++reg)
        r3v[reg] = *(const float4*)&r3s[w * 16 + quad * 4 + reg][0];

    for (int i8 = 0; i8 < 8; ++i8) {
        const int kt  = kt0 + i8;
        const int cur = i8 & 1;
        const bool more = (i8 + 1 < 8);
        if (more) {
            const int k0 = (kt + 1) * 64;
            const int nb = cur ^ 1;
            const int cl  = scp ^ (sr & 7);
            const ushort_t* g = qkv + (size_t)(b * SS + k0 + sr) * (3 * DD) + DD + h * HD + cl * 8;
            __builtin_amdgcn_global_load_lds(
                (const __attribute__((address_space(1))) unsigned*)g,
                (__attribute__((address_space(3))) unsigned*)(&Ks[nb][0] + (size_t)t * 8), 16, 0, 0);
            const int r2  = sr + 32;
            const int cl2 = scp ^ (r2 & 7);
            const ushort_t* g2 = qkv + (size_t)(b * SS + k0 + r2) * (3 * DD) + DD + h * HD + cl2 * 8;
            __builtin_amdgcn_global_load_lds(
                (const __attribute__((address_space(1))) unsigned*)g2,
                (__attribute__((address_space(3))) unsigned*)(&Ks[nb][0] + (size_t)(t + 256) * 8), 16, 0, 0);
            const ushort_t* gv = qkv + (size_t)(b * SS + k0 + 2 * vkp) * (3 * DD) + 2 * DD + h * HD + vdg * 8;
            va = *(const short8*)gv;
            vb = *(const short8*)(gv + 3 * DD);
        }

        f32x4 sacc[4] = {};
#pragma unroll
        for (int kc = 0; kc < 2; ++kc) {
            const short8 qv = kc ? qf1 : qf0;
#pragma unroll
            for (int nt = 0; nt < 4; ++nt) {
                const int row = nt * 16 + l15;
                const int cp  = (kc * 4 + quad) ^ (row & 7);
                const short8 kf = *(const short8*)(&Ks[cur][0] + (size_t)row * 64 + cp * 8);
                sacc[nt] = __builtin_amdgcn_mfma_f32_16x16x32_bf16(qv, kf, sacc[nt], 0, 0, 0);
            }
        }

#pragma unroll
        for (int reg = 0; reg < 4; ++reg) {
            const int qloc = w * 16 + quad * 4 + reg;
            const unsigned cds = codes[((size_t)(b * SS + q0 + qloc) * 16 + kt) * 16 + l15];
            const float4 r4 = r3v[reg];
#pragma unroll
            for (int nt = 0; nt < 4; ++nt) {
                const unsigned c = (cds >> (8 * nt)) & 0xff;
                float rvv = (c == 0) ? r4.x : (c == 1) ? r4.y : (c == 2) ? r4.z : r4.w;
                const float p = __expf((sacc[nt][reg] + rvv) * 0.125f);
                l_run[reg] += p;
                Ps[(size_t)qloc * 72 + nt * 16 + l15] = f2bf_rne(p);
            }
        }

#pragma unroll
        for (int kc = 0; kc < 2; ++kc) {
            const short8 pf = *(const short8*)(Ps + (size_t)(w * 16 + l15) * 72 + kc * 32 + quad * 8);
#pragma unroll
            for (int dt = 0; dt < 4; ++dt) {
                const int d  = dt * 16 + l15;
                const int dg = d >> 3;
                const int kps0 = (kc * 16 + quad * 4) ^ ((dg & 7) * 4);
                const short8 vf = *(const short8*)((const ushort_t*)&Vt2[cur][(size_t)d * 36 + kps0]);
                oacc[dt] = __builtin_amdgcn_mfma_f32_16x16x32_bf16(pf, vf, oacc[dt], 0, 0, 0);
            }
        }

        if (more) {
            const int nb = cur ^ 1;
#pragma unroll
            for (int i = 0; i < 8; ++i)
                Vt2[nb][(size_t)(vdg * 8 + i) * 36 + vkps] =
                    (unsigned)(ushort_t)va[i] | ((unsigned)(ushort_t)vb[i] << 16);
            __syncthreads();
        }
    }

    ushort_t* Op = Opart + (size_t)ks * BSD;
    float* lp = lpart + (size_t)ks * BS2 * HH;
#pragma unroll
    for (int reg = 0; reg < 4; ++reg) {
        float ls = l_run[reg];
        ls += __shfl_xor(ls, 1);
        ls += __shfl_xor(ls, 2);
        ls += __shfl_xor(ls, 4);
        ls += __shfl_xor(ls, 8);
        const int orow = b * SS + q0 + w * 16 + quad * 4 + reg;
#pragma unroll
        for (int dt = 0; dt < 4; ++dt)
            Op[(size_t)orow * DD + h * HD + dt * 16 + l15] = f2bf_rne(oacc[dt][reg]);
        if (l15 == 0) lp[(size_t)orow * HH + h] = ls;
    }
}

// ---------------------------------------------------------------------------
// attn_merge: att_bf = (O0 + O1) / (l0 + l1), bf16 partials in, bf16 out.
// ---------------------------------------------------------------------------
__global__ __launch_bounds__(256) void attn_merge(
    const ushort_t* __restrict__ Opart, const float* __restrict__ lpart,
    ushort_t* __restrict__ att_bf)
{
    int i = blockIdx.x * 256 + threadIdx.x;
    int row = (i * 4) / DD;
    int h   = ((i * 4) % DD) >> 6;
    float l0 = lpart[(size_t)row * HH + h];
    float l1 = lpart[(size_t)BS2 * HH + (size_t)row * HH + h];
    float inv = 1.0f / (l0 + l1);
    ushort4 a = ((const ushort4*)Opart)[i];
    ushort4 b = ((const ushort4*)(Opart + BSD))[i];
    ushort4 o;
    o.x = f2bf_rne((bf2f(a.x) + bf2f(b.x)) * inv);
    o.y = f2bf_rne((bf2f(a.y) + bf2f(b.y)) * inv);
    o.z = f2bf_rne((bf2f(a.z) + bf2f(b.z)) * inv);
    o.w = f2bf_rne((bf2f(a.w) + bf2f(b.w)) * inv);
    ((ushort4*)att_bf)[i] = o;
}

// ---------------------------------------------------------------------------
extern "C" void kernel_launch(void* const* d_in, const int* in_sizes, int n_in,
                              void* d_out, int out_size, void* d_ws, size_t ws_size,
                              hipStream_t stream) {
    const float* inp   = (const float*)d_in[0];
    const uchar_t* amask = (const uchar_t*)d_in[1];
    const int*   relm  = (const int*)d_in[2];
    const float* qkv_w = (const float*)d_in[3];
    const float* rel_A = (const float*)d_in[4];
    const float* o_w   = (const float*)d_in[5];
    const float* w1    = (const float*)d_in[6];
    const float* b1    = (const float*)d_in[7];
    const float* w2    = (const float*)d_in[8];
    const float* b2    = (const float*)d_in[9];
    const float* ln1_g = (const float*)d_in[10];
    const float* ln1_b = (const float*)d_in[11];
    const float* ln2_g = (const float*)d_in[12];
    const float* ln2_b = (const float*)d_in[13];
    float* out = (float*)d_out;

    // workspace layout (weight bf16 buffers MUST stay contiguous for cvt)
    char* p = (char*)d_ws;
    ushort_t* x_bf   = (ushort_t*)p; p += BSD * 2;
    ushort_t* att_bf = (ushort_t*)p; p += BSD * 2;
    ushort_t* h_bf   = (ushort_t*)p; p += BSD * 2;
    ushort_t* ff_bf  = (ushort_t*)p; p += (size_t)BS2 * DFF * 2;
    ushort_t* qkvw_bf= (ushort_t*)p; p += (size_t)3 * DD * DD * 2;
    ushort_t* ow_bf  = (ushort_t*)p; p += (size_t)DD * DD * 2;
    ushort_t* w1_bf  = (ushort_t*)p; p += (size_t)DFF * DD * 2;
    ushort_t* w2_bf  = (ushort_t*)p; p += (size_t)DD * DFF * 2;
    ushort_t* qkv_bf = (ushort_t*)p; p += (size_t)BS2 * 3 * DD * 2;
    float*    resid  = (float*)p;    p += BSD * 4;
    ushort_t* pool   = (ushort_t*)p; p += 4 * BSD * 2;
    ushort_t* Opart  = (ushort_t*)p; p += 2 * BSD * 2;
    float*    lpart  = (float*)p;    p += (size_t)2 * BS2 * HH * 4;
    unsigned* codes  = (unsigned*)p; p += (size_t)BB * SS * SS;

    // 0. prep: weight cvt + codes + LN1, one launch
    prep_kernel<<<PREP_CVT + PREP_CODES + PREP_LN, 256, 0, stream>>>(
        qkv_w, o_w, w1, w2, qkvw_bf, relm, amask, codes,
        inp, ln1_g, ln1_b, x_bf);

    // 1. QKV = x @ qkv_w.T -> bf16 : grid (18,32) = 576 blocks
    gemm_tile<false, true, false, false>
        <<<dim3(3 * DD / 128, BS2 / 64, 1), 256, 0, stream>>>(
        x_bf, qkvw_bf, nullptr, qkv_bf, BS2, 3 * DD, DD, DD);

    // 2. attention, k-split x2 : grid 768 ; merge -> bf16
    attn_mfma_kernel<<<BB * HH * 16 * 2, 256, 0, stream>>>(
        qkv_bf, codes, rel_A, Opart, lpart);
    attn_merge<<<(int)(BSD / 4 / 256), 256, 0, stream>>>(Opart, lpart, att_bf);

    // 3. o-proj bf16 partials (Z=2) : grid (6,32,2) = 384 blocks
    gemm_tile<false, false, false, true>
        <<<dim3(DD / 128, BS2 / 64, 2), 256, 0, stream>>>(
        att_bf, ow_bf, nullptr, pool, BS2, DD, DD, DD / 2);

    // 4. fused: resid = inp + p0 + p1 ; h_bf = LN2(resid)
    merge2_ln_kernel<<<BS2, 256, 0, stream>>>(
        pool, inp, ln2_g, ln2_b, resid, h_bf);

    // 5. ff = relu(h @ w1.T + b1) -> bf16 : grid (24,32) = 768 blocks
    gemm_tile<true, true, true, false>
        <<<dim3(DFF / 128, BS2 / 64, 1), 256, 0, stream>>>(
        h_bf, w1_bf, b1, ff_bf, BS2, DFF, DD, DD);

    // 6. MLP2 bf16 partials (Z=4) : grid (6,32,4) = 768 blocks
    gemm_tile<false, false, false, true>
        <<<dim3(DD / 128, BS2 / 64, 4), 256, 0, stream>>>(
        ff_bf, w2_bf, nullptr, pool, BS2, DD, DFF, DFF / 4);

    // 7. out = resid + b2 + p0..p3
    merge4_kernel<<<(int)(BSD / 4 / 256), 256, 0, stream>>>(
        pool, resid, b2, out, (int)(BSD / 4));
}